// Round 5
// baseline (126.559 us; speedup 1.0000x reference)
//
#include <hip/hip_runtime.h>
#include <stdint.h>

// BacklashNet: per-row nonlinear scan (backlash/hysteresis), fully fused,
// double-buffered LDS, async global->LDS staging, m201-style raw barriers.
//
// R1 (70 us): fused single pass; duty-cycle-bound (phase-aligned bursts).
// R2 (97 us, REGRESSION): register prefetch spilled (VGPR capped 128).
// R3 (42 us): global_load_lds double-buffer + counted vmcnt, but every
//   __syncthreads() drains vmcnt(0) -> prefetch dead.
// R4 (42.8 us, NULL): inline-asm barriers carried a "memory" clobber ->
//   the memory legalizer inserted s_waitcnt vmcnt(0) lgkmcnt(0) BEFORE the
//   asm anyway (asm-with-memory-clobber may read global_load_lds' LDS
//   dest). Counters bit-identical to R3 => emitted waits unchanged.
// R5: the verified m201/HipKittens idiom — __builtin_amdgcn_s_barrier()
//   (IntrNoMem: legalizer inserts nothing) + clobber-FREE counted
//   s_waitcnt asm, pinned with __builtin_amdgcn_sched_barrier(0) on both
//   sides (guide rule #18: sched_barrier is the fence, not "memory").
//   Per-wave VMEM FIFO: L0,L1,[S0],L2,[S1],L3,[S2]
//     row0 vmcnt(16)  (newer = L1)
//     row1 vmcnt(32)  (newer = S0+L2)
//     row2 vmcnt(32)  (newer = S1+L3)
//     row3 vmcnt(16)  (newer = S2)
//   Cross-wave LDS dependencies (chunk c mod 8 >= 4 is staged by wave1,
//   se0[c-1] crosses the wave boundary at c=64) => each barrier is
//   wait-own-counter THEN s_barrier: after the barrier, both waves' ops
//   are retired. Stitch path keeps __syncthreads (full drain safe there).
//
// Verified machinery kept byte-identical (passed, absmax 7.8e-3):
//   - source-side XOR swizzle for linear global_load_lds dest;
//     read-side slot(c,f)=c*16+(f^(c&15)): 0 bank conflicts measured
//   - bit-exact bstep (__f*_rn, reference op order)
//   - acceptance: chunk c+1 valid iff e0[c]==e1[c] bitwise; all-converged
//     => pass B outputs exact; failure -> uniform cooperative stitch.

namespace {

constexpr int kB  = 2048;
constexpr int kT  = 8192;
constexpr int kNC = 128;           // chunks per row == threads per block
constexpr int kRPB = 4;            // rows per block
constexpr int kGrid = kB / kRPB;   // 512 blocks = 2/CU, one generation

// Publish this wave's LDS writes, then rendezvous. No vmcnt drain: barrier
// builtin is IntrNoMem, waitcnt asm has no memory clobber; sched_barrier(0)
// pins all surrounding memory ops in the machine schedule.
__device__ __forceinline__ void bar_lgkm() {
  __builtin_amdgcn_sched_barrier(0);
  asm volatile("s_waitcnt lgkmcnt(0)");
  __builtin_amdgcn_s_barrier();
  __builtin_amdgcn_sched_barrier(0);
}

// Row-start rendezvous: wait own counted vmcnt (N = ops issued after the
// loads being waited on, FIFO retirement), then barrier -> both waves'
// stage loads have landed in LDS.
#define ROW_WAIT(N)                                   \
  do {                                                \
    __builtin_amdgcn_sched_barrier(0);                \
    asm volatile("s_waitcnt vmcnt(" #N ")");          \
    __builtin_amdgcn_s_barrier();                     \
    __builtin_amdgcn_sched_barrier(0);                \
  } while (0)

__device__ __forceinline__ float bstep(float xv, float prev, float m_lo, float m_up,
                                       float mlc, float muc) {
  float A1 = __fmul_rn(m_lo, xv);
  float B1 = __fadd_rn(A1, mlc);
  float A2 = __fmul_rn(m_up, xv);
  float B2 = __fadd_rn(A2, muc);
  float C  = __fadd_rn(__fadd_rn(B1, A2), muc);
  float u  = __fsub_rn(prev, A2);
  bool  f1 = (B1 <= prev);
  bool  f2 = (u <= muc);
  float hi = f2 ? C  : B1;
  float lo = f2 ? B2 : prev;
  return f1 ? hi : lo;
}

// Async-stage one row: 16 x global_load_lds(16B) per thread, linear LDS
// dest (slot s = j*128 + tid), pre-swizzled global source.
__device__ __forceinline__ void issue_row(const float* __restrict__ xrow,
                                          float4* __restrict__ buf, int tid) {
#pragma unroll
  for (int j = 0; j < 16; ++j) {
    const int s  = j * 128 + tid;
    const int cc = s >> 4, fs = s & 15;
    const int g  = cc * 16 + (fs ^ (cc & 15));
    __builtin_amdgcn_global_load_lds(
        (const __attribute__((address_space(1))) uint32_t*)(xrow + 4 * (size_t)g),
        (__attribute__((address_space(3))) uint32_t*)(buf + s),
        16, 0, 0);
  }
}

// Process one fully-staged row out of sb. If !kLast, ends with a raw
// lgkm-barrier so the caller may immediately re-stage sb.
template <bool kLast>
__device__ __forceinline__ void process_row(
    float4* __restrict__ sb, float* __restrict__ se0, float* __restrict__ se1,
    int* __restrict__ sflag, float* __restrict__ sfix,
    float* __restrict__ out, int r, int c, float p0r,
    float m_lo, float m_up, float mlc, float muc) {
  // my chunk -> registers (conflict-free swizzled b128 column reads)
  float4 xb[16];
#pragma unroll
  for (int f = 0; f < 16; ++f) xb[f] = sb[c * 16 + (f ^ (c & 15))];

  // pass A: exit from guess entry
  float pa = (c == 0) ? p0r : 0.0f;
#pragma unroll
  for (int q = 0; q < 16; ++q) {
    pa = bstep(xb[q].x, pa, m_lo, m_up, mlc, muc);
    pa = bstep(xb[q].y, pa, m_lo, m_up, mlc, muc);
    pa = bstep(xb[q].z, pa, m_lo, m_up, mlc, muc);
    pa = bstep(xb[q].w, pa, m_lo, m_up, mlc, muc);
  }
  se0[c] = pa;
  bar_lgkm();  // publish se0; prefetch loads stay in flight

  // pass B: run from e0[c-1], write outputs in-place over x in LDS
  float pb = (c == 0) ? p0r : se0[c - 1];
#pragma unroll
  for (int q = 0; q < 16; ++q) {
    float o0 = bstep(xb[q].x, pb, m_lo, m_up, mlc, muc);
    float o1 = bstep(xb[q].y, o0, m_lo, m_up, mlc, muc);
    float o2 = bstep(xb[q].z, o1, m_lo, m_up, mlc, muc);
    float o3 = bstep(xb[q].w, o2, m_lo, m_up, mlc, muc);
    sb[c * 16 + (q ^ (c & 15))] = make_float4(o0, o1, o2, o3);
    pb = o3;
  }
  se1[c] = pb;

  // acceptance: chunk c+1 valid iff e0[c]==e1[c] bitwise
  const bool conv = (c == kNC - 1) || (pa == pb);
  const unsigned long long bal = __ballot(conv);
  if ((c & 63) == 0) sflag[c >> 6] = (bal == ~0ull);
  bar_lgkm();  // publish se1, sb outputs, flags

  if (!(sflag[0] && sflag[1])) {
    // Rare exact stitch (uniform branches; decisions from LDS broadcasts).
    // __syncthreads' full drains are correctness-safe here.
    float t = se1[0];
    for (int cc = 1; cc < kNC; ++cc) {
      const bool valid = (se0[cc - 1] == t);
      if (valid) {
        t = se1[cc];
      } else {
        __syncthreads();
        if (c == cc) {
          float pf = t;
#pragma unroll
          for (int q = 0; q < 16; ++q) {
            float o0 = bstep(xb[q].x, pf, m_lo, m_up, mlc, muc);
            float o1 = bstep(xb[q].y, o0, m_lo, m_up, mlc, muc);
            float o2 = bstep(xb[q].z, o1, m_lo, m_up, mlc, muc);
            float o3 = bstep(xb[q].w, o2, m_lo, m_up, mlc, muc);
            sb[c * 16 + (q ^ (c & 15))] = make_float4(o0, o1, o2, o3);
            pf = o3;
          }
          *sfix = pf;
        }
        __syncthreads();
        t = *sfix;
      }
    }
    __syncthreads();  // publish rewritten columns
  }

  // coalesced flush: LDS -> out (inverse transpose), 1 KB/instr/wave
  float4* o4 = reinterpret_cast<float4*>(out + (size_t)r * kT);
#pragma unroll
  for (int j = 0; j < 16; ++j) {
    const int g  = j * 128 + c;
    const int cc = g >> 4, f = g & 15;
    o4[g] = sb[cc * 16 + (f ^ (cc & 15))];
  }
  if (!kLast) {
    // flush ds_reads retired (lgkm) on all waves -> sb safe to re-stage
    bar_lgkm();
  }
}

__global__ __launch_bounds__(128, 2) void backlash_fused(
    const float* __restrict__ x, const float* __restrict__ p0,
    const float* __restrict__ w, float* __restrict__ out) {
  __shared__ float4 sb[2][kNC * 16];     // 2 x 32 KB double buffer
  __shared__ float  se0[kNC], se1[kNC];
  __shared__ int    sflag[2];
  __shared__ float  sfix;

  const int c  = threadIdx.x;
  const int r0 = blockIdx.x * kRPB;
  const float m_lo = w[0], m_up = w[1];
  const float mlc = __fmul_rn(m_lo, w[2]), muc = __fmul_rn(m_up, w[3]);

  // prologue: rows 0 and 1 in flight (16 + 16 outstanding per thread)
  issue_row(x + (size_t)r0 * kT,       sb[0], c);
  issue_row(x + (size_t)(r0 + 1) * kT, sb[1], c);

  // row 0 — newer-than-L0 = L1(16)
  ROW_WAIT(16);
  process_row<false>(sb[0], se0, se1, sflag, &sfix, out, r0, c, p0[r0],
                     m_lo, m_up, mlc, muc);
  issue_row(x + (size_t)(r0 + 2) * kT, sb[0], c);

  // row 1 — newer-than-L1 = S0(16)+L2(16)
  ROW_WAIT(32);
  process_row<false>(sb[1], se0, se1, sflag, &sfix, out, r0 + 1, c, p0[r0 + 1],
                     m_lo, m_up, mlc, muc);
  issue_row(x + (size_t)(r0 + 3) * kT, sb[1], c);

  // row 2 — newer-than-L2 = S1(16)+L3(16)
  ROW_WAIT(32);
  process_row<false>(sb[0], se0, se1, sflag, &sfix, out, r0 + 2, c, p0[r0 + 2],
                     m_lo, m_up, mlc, muc);

  // row 3 — newer-than-L3 = S2(16)
  ROW_WAIT(16);
  process_row<true>(sb[1], se0, se1, sflag, &sfix, out, r0 + 3, c, p0[r0 + 3],
                    m_lo, m_up, mlc, muc);
}

}  // namespace

extern "C" void kernel_launch(void* const* d_in, const int* in_sizes, int n_in,
                              void* d_out, int out_size, void* d_ws, size_t ws_size,
                              hipStream_t stream) {
  const float* x  = (const float*)d_in[0];   // (B, T, 1) fp32
  const float* p0 = (const float*)d_in[1];   // (B, 1, 1) fp32
  const float* w  = (const float*)d_in[2];   // (4,) fp32
  float* out = (float*)d_out;                // (B, T, 1) fp32
  (void)in_sizes; (void)n_in; (void)out_size; (void)d_ws; (void)ws_size;

  backlash_fused<<<kGrid, kNC, 0, stream>>>(x, p0, w, out);
}